// Round 1
// baseline (10389.337 us; speedup 1.0000x reference)
//
#include <hip/hip_runtime.h>
#include <hip/hip_cooperative_groups.h>
#include <hip/hip_bf16.h>
#include <math.h>

namespace cg = cooperative_groups;

#define NB 64
#define NT 512
#define NDIN 256
#define NH 1024
#define NG 4096
#define NDOUT 256

// grid roles: [0,64) z+combine, [64,80) proj, [80,88) out-reduce
#define GRIDN 88
#define LDSB 148992   // 128K reduce + 16K zfin + 1.5K tables

typedef __attribute__((ext_vector_type(8))) short short8;
typedef __attribute__((ext_vector_type(4))) float float4v;

__device__ __forceinline__ float sigf(float v) { return 1.0f / (1.0f + expf(-v)); }

__device__ __forceinline__ unsigned short bf_hi(float v, float* back) {
    __hip_bfloat16 b = __float2bfloat16(v);
    *back = __bfloat162float(b);
    union { __hip_bfloat16 b; unsigned short u; } cv; cv.b = b;
    return cv.u;
}

__global__ void zero_kernel(float* __restrict__ p, int n) {
    int i = blockIdx.x * 256 + threadIdx.x;
    if (i < n) p[i] = 0.0f;
}

// W (= [Wx;Wh], 1280 x 4096) -> B-frag order [nb(256)][ku(40)][lane(64)][j(8)], hi/lo
__global__ void packW_kernel(const float* __restrict__ Wx, const float* __restrict__ Wh,
                             unsigned short* __restrict__ W0f, unsigned short* __restrict__ W1f) {
    int e = blockIdx.x * 256 + threadIdx.x;
    if (e >= 1280 * 4096) return;
    int k = e >> 12, n = e & 4095;
    float w = (k < NDIN) ? Wx[(size_t)k * NG + n] : Wh[(size_t)(k - NDIN) * NG + n];
    float back;
    unsigned short w0 = bf_hi(w, &back);
    unsigned short w1 = bf_hi(w - back, &back);
    int nb = n >> 4, nl = n & 15, ku = k >> 5, kr = k & 31;
    int lane = (kr >> 3) * 16 + nl, j = kr & 7;
    size_t off = (((size_t)nb * 40 + ku) * 64 + lane) * 8 + j;
    W0f[off] = w0; W1f[off] = w1;
}

// x ([64][512][256]) -> A-frag order [t][ku(8)][mb(4)][lane(64)][j(8)], hi/lo
__global__ void packX_kernel(const float* __restrict__ x,
                             unsigned short* __restrict__ xf0, unsigned short* __restrict__ xf1) {
    int e = blockIdx.x * 256 + threadIdx.x;
    if (e >= NB * NT * NDIN) return;
    int k = e & 255, t = (e >> 8) & 511, m = e >> 17;
    float v = x[e];
    float back;
    unsigned short a0 = bf_hi(v, &back);
    unsigned short a1 = bf_hi(v - back, &back);
    int ku = k >> 5, kr = k & 31, mb = m >> 4;
    int lane = (kr >> 3) * 16 + (m & 15), j = kr & 7;
    size_t off = ((((size_t)t * 8 + ku) * 4 + mb) * 64 + lane) * 8 + j;
    xf0[off] = a0; xf1[off] = a1;
}

// Wo (1024 x 256) -> B-frag order [nb(16)][ku(32)][lane(64)][j(8)], hi/lo
__global__ void packWo_kernel(const float* __restrict__ Wo,
                              unsigned short* __restrict__ Wo0f, unsigned short* __restrict__ Wo1f) {
    int e = blockIdx.x * 256 + threadIdx.x;
    if (e >= NH * NDOUT) return;
    int k = e >> 8, n = e & 255;
    float w = Wo[e];
    float back;
    unsigned short w0 = bf_hi(w, &back);
    unsigned short w1 = bf_hi(w - back, &back);
    int nb = n >> 4, nl = n & 15, ku = k >> 5, kr = k & 31;
    int lane = (kr >> 3) * 16 + nl, j = kr & 7;
    size_t off = (((size_t)nb * 32 + ku) * 64 + lane) * 8 + j;
    Wo0f[off] = w0; Wo1f[off] = w1;
}

__device__ __forceinline__ const unsigned short* abase(
    const unsigned short* xf0, const unsigned short* xf1,
    const unsigned short* hf, int t, int buf, int ku, int v) {
    if (ku < 8) return (v ? xf1 : xf0) + ((size_t)t * 8 + ku) * 2048;
    return hf + ((size_t)(v * 2 + buf) * 32 + (ku - 8)) * 2048;
}

// Persistent cooperative kernel: one launch, loop over t, grid.sync() per step.
// All blocks co-resident (88 blocks, 1/CU via 148KB LDS) -> block->XCD mapping is
// pinned, so each z-block's 327KB W slice stays L2-resident across all steps.
// All cross-block dataflow (hf, opart) crosses a grid.sync boundary.
__global__ __launch_bounds__(512, 2) void persist_kernel(
    const unsigned short* __restrict__ W0f, const unsigned short* __restrict__ W1f,
    const unsigned short* __restrict__ xf0, const unsigned short* __restrict__ xf1,
    const unsigned short* __restrict__ Wo0f, const unsigned short* __restrict__ Wo1f,
    unsigned short* __restrict__ hf, float* __restrict__ cst,
    float* __restrict__ opart, const float* __restrict__ bias,
    const float* __restrict__ bo, float* __restrict__ out)
{
    cg::grid_group grid = cg::this_grid();
    extern __shared__ char dynlds[];
    float* red  = (float*)dynlds;                    // [8][4096]
    float* zfin = (float*)(dynlds + 131072);         // [4096]
    const unsigned short** tabA = (const unsigned short**)(dynlds + 147456); // [96]
    const unsigned short** tabW = tabA + 96;

    const int bid = blockIdx.x, tid = threadIdx.x;
    const int lane = tid & 63, w = tid >> 6;

    // proj blocks: t-invariant pointer tables, built once. buf-dependence is a
    // uniform +buf*65536-element offset applied in the loop.
    if (bid >= 64 && bid < 80) {
        const int pnb = bid - 64;
        for (int i = tid; i < 96; i += 512) {
            int q = i / 32, ku = i % 32, v = (q == 2);
            tabA[i] = hf + (((size_t)(v * 2) * 32 + ku) * 4) * 512;
            tabW[i] = ((q == 1) ? Wo1f : Wo0f) + (size_t)pnb * 32 * 512 + (size_t)ku * 512;
        }
        __syncthreads();
    }

    for (int t = 0; t <= NT + 1; ++t) {
        const int buf = t & 1, nbuf = (t + 1) & 1;

        if (bid < 64) {
            if (t < NT) {
                // ---- z + block-local combine: 16 h-cols (jt), all 4 gates, all rows ----
                const int jt = bid;
                float4v acc[4][4];                            // [mb][gate]
                #pragma unroll
                for (int mb = 0; mb < 4; ++mb)
                    #pragma unroll
                    for (int g = 0; g < 4; ++g)
                        acc[mb][g] = (float4v){0.f, 0.f, 0.f, 0.f};

                const int ku0 = w * 5;                        // wave-private K slice
                #pragma unroll
                for (int i = 0; i < 5; ++i) {
                    const int ku = ku0 + i;
                    short8 A0[4], A1[4], Wh[4], Wl[4];
                    #pragma unroll
                    for (int mb = 0; mb < 4; ++mb) {
                        A0[mb] = *(const short8*)(abase(xf0, xf1, hf, t, buf, ku, 0) + mb * 512 + lane * 8);
                        A1[mb] = *(const short8*)(abase(xf0, xf1, hf, t, buf, ku, 1) + mb * 512 + lane * 8);
                    }
                    #pragma unroll
                    for (int g = 0; g < 4; ++g) {
                        size_t off = (((size_t)(g * 64 + jt) * 40 + ku) * 64 + lane) * 8;
                        Wh[g] = *(const short8*)(W0f + off);
                        Wl[g] = *(const short8*)(W1f + off);
                    }
                    #pragma unroll
                    for (int mb = 0; mb < 4; ++mb)
                        #pragma unroll
                        for (int g = 0; g < 4; ++g) {
                            acc[mb][g] = __builtin_amdgcn_mfma_f32_16x16x32_bf16(A0[mb], Wh[g], acc[mb][g], 0, 0, 0);
                            acc[mb][g] = __builtin_amdgcn_mfma_f32_16x16x32_bf16(A0[mb], Wl[g], acc[mb][g], 0, 0, 0);
                            acc[mb][g] = __builtin_amdgcn_mfma_f32_16x16x32_bf16(A1[mb], Wh[g], acc[mb][g], 0, 0, 0);
                        }
                }

                // cross-wave splitK reduce via LDS
                {
                    float* slab = red + w * 4096;
                    #pragma unroll
                    for (int mb = 0; mb < 4; ++mb)
                        #pragma unroll
                        for (int g = 0; g < 4; ++g)
                            *(float4v*)&slab[((mb * 4 + g) * 64 + lane) * 4] = acc[mb][g];
                }
                __syncthreads();
                for (int s = tid; s < 1024; s += 512) {
                    float4v sum = (float4v){0.f, 0.f, 0.f, 0.f};
                    #pragma unroll
                    for (int ww = 0; ww < 8; ++ww)
                        sum = sum + *(const float4v*)&red[ww * 4096 + s * 4];
                    *(float4v*)&zfin[s * 4] = sum;
                }
                __syncthreads();

                // block-local gate math + cell update + h-frag write
                for (int e = tid; e < 1024; e += 512) {
                    const int row = e >> 4, col = e & 15;
                    const int j = jt * 16 + col;
                    const int mb = row >> 4, q4 = (row >> 2) & 3, r = row & 3;
                    const int ln = q4 * 16 + col;
                    float zi = zfin[((mb * 4 + 0) * 64 + ln) * 4 + r] + bias[j];
                    float zf = zfin[((mb * 4 + 1) * 64 + ln) * 4 + r] + bias[NH + j];
                    float zg = zfin[((mb * 4 + 2) * 64 + ln) * 4 + r] + bias[2 * NH + j];
                    float zo = zfin[((mb * 4 + 3) * 64 + ln) * 4 + r] + bias[3 * NH + j];
                    float iv = sigf(zi), fv = sigf(zf), gv = tanhf(zg), ov = sigf(zo);
                    const size_t ci = (size_t)row * NH + j;   // block-exclusive columns
                    float cv = fv * cst[ci] + iv * gv;
                    cst[ci] = cv;
                    float hv = ov * tanhf(cv);
                    float back;
                    unsigned short h0 = bf_hi(hv, &back);
                    unsigned short h1 = bf_hi(hv - back, &back);
                    const int ku = j >> 5, kr = j & 31;
                    const int lane2 = (kr >> 3) * 16 + (row & 15), jj = kr & 7;
                    size_t base = (((size_t)nbuf * 32 + ku) * 4 + mb) * 512 + lane2 * 8 + jj;
                    hf[base] = h0;
                    hf[base + 131072] = h1;                   // v=1 stride
                }
            }
        } else if (bid < 80) {
            // ---- projection of hf[buf] (= h of step t-1) -> opart[t&1] ----
            if (t >= 1 && t <= NT) {
                const int pnb = bid - 64;
                const size_t bufofs = (size_t)buf * 65536;    // (buf*32)*4*512 elements
                const int pksl = w >> 2, mbw = w & 3;
                float4v pacc = (float4v){0.f, 0.f, 0.f, 0.f};
                #pragma unroll 6
                for (int i = pksl * 48; i < pksl * 48 + 48; ++i) {
                    short8 A = *(const short8*)(tabA[i] + bufofs + mbw * 512 + lane * 8);
                    short8 B = *(const short8*)(tabW[i] + lane * 8);
                    pacc = __builtin_amdgcn_mfma_f32_16x16x32_bf16(A, B, pacc, 0, 0, 0);
                }
                const int q4 = lane >> 4, nl16 = lane & 15;
                float* op = opart + (size_t)(t & 1) * 32768;
                #pragma unroll
                for (int r = 0; r < 4; ++r)
                    op[((size_t)(pksl * 64 + mbw * 16 + q4 * 4 + r)) * NDOUT + pnb * 16 + nl16] = pacc[r];
            }
        } else {
            // ---- out-reduce of opart[(t-1)&1] (= proj of h step t-2) -> row t-2 ----
            if (t >= 2) {
                const int ob = bid - 80;
                const float* op = opart + (size_t)((t - 1) & 1) * 32768;
                int idx = ob * 512 + tid;                     // [0,4096)
                int m = idx >> 6, oc4 = (idx & 63) * 4;
                float4v s0 = *(const float4v*)&op[(size_t)m * NDOUT + oc4];
                float4v s1 = *(const float4v*)&op[(size_t)(64 + m) * NDOUT + oc4];
                float4v bv = *(const float4v*)&bo[oc4];
                float4v v = s0 + s1 + bv;
                float4v rr;
                rr[0] = fmaxf(v[0], 0.f); rr[1] = fmaxf(v[1], 0.f);
                rr[2] = fmaxf(v[2], 0.f); rr[3] = fmaxf(v[3], 0.f);
                *(float4v*)&out[((size_t)m * NT + (t - 2)) * NDOUT + oc4] = rr;
            }
        }

        grid.sync();
    }
}

extern "C" void kernel_launch(void* const* d_in, const int* in_sizes, int n_in,
                              void* d_out, int out_size, void* d_ws, size_t ws_size,
                              hipStream_t stream) {
    const float* x  = (const float*)d_in[0];
    const float* Wx = (const float*)d_in[1];
    const float* Wh = (const float*)d_in[2];
    const float* b  = (const float*)d_in[3];
    const float* Wo = (const float*)d_in[4];
    const float* bo = (const float*)d_in[5];
    float* out = (float*)d_out;
    char* ws = (char*)d_ws;

    size_t off = 0;
    float* cst    = (float*)(ws + off);               off += (size_t)NB * NH * 4;               // 256 KB
    unsigned short* hf = (unsigned short*)(ws + off); off += (size_t)2 * 2 * 32 * 4 * 512 * 2;  // 512 KB
    size_t zero_floats = off / 4;                     // cst + hf zeroed
    float* opart = (float*)(ws + off);                off += (size_t)2 * 2 * NB * NDOUT * 4;    // 256 KB
    unsigned short* W0f = (unsigned short*)(ws + off); off += (size_t)1280 * 4096 * 2;
    unsigned short* W1f = (unsigned short*)(ws + off); off += (size_t)1280 * 4096 * 2;
    unsigned short* Wo0f = (unsigned short*)(ws + off); off += (size_t)NH * NDOUT * 2;
    unsigned short* Wo1f = (unsigned short*)(ws + off); off += (size_t)NH * NDOUT * 2;
    unsigned short* xf0 = (unsigned short*)(ws + off); off += (size_t)NB * NT * NDIN * 2;
    unsigned short* xf1 = (unsigned short*)(ws + off); off += (size_t)NB * NT * NDIN * 2;

    zero_kernel<<<(int)((zero_floats + 255) / 256), 256, 0, stream>>>((float*)ws, (int)zero_floats);
    packW_kernel<<<(1280 * 4096 + 255) / 256, 256, 0, stream>>>(Wx, Wh, W0f, W1f);
    packX_kernel<<<(NB * NT * NDIN + 255) / 256, 256, 0, stream>>>(x, xf0, xf1);
    packWo_kernel<<<(NH * NDOUT + 255) / 256, 256, 0, stream>>>(Wo, Wo0f, Wo1f);

    void* args[] = {(void*)&W0f, (void*)&W1f, (void*)&xf0, (void*)&xf1,
                    (void*)&Wo0f, (void*)&Wo1f, (void*)&hf, (void*)&cst,
                    (void*)&opart, (void*)&b, (void*)&bo, (void*)&out};
    hipLaunchCooperativeKernel((void*)persist_kernel, dim3(GRIDN), dim3(512),
                               args, (unsigned)LDSB, stream);
}

// Round 2
// 7295.015 us; speedup vs baseline: 1.4242x; 1.4242x over previous
//
#include <hip/hip_runtime.h>
#include <hip/hip_bf16.h>
#include <math.h>

#define NB 64
#define NT 512
#define NDIN 256
#define NH 1024
#define NG 4096
#define NDOUT 256

// grid roles: [0,64) z+combine, [64,80) proj, [80,88) out-reduce
#define GRIDN 88
#define LDSB 148992   // 128K reduce + 16K zfin + 1.5K tables

typedef __attribute__((ext_vector_type(8))) short short8;
typedef __attribute__((ext_vector_type(4))) float float4v;

__device__ __forceinline__ float sigf(float v) { return 1.0f / (1.0f + expf(-v)); }

__device__ __forceinline__ unsigned short bf_hi(float v, float* back) {
    __hip_bfloat16 b = __float2bfloat16(v);
    *back = __bfloat162float(b);
    union { __hip_bfloat16 b; unsigned short u; } cv; cv.b = b;
    return cv.u;
}

// ---- device-coherent (LLC) access helpers: sc0 sc1 = bypass L1+L2 ----
// 8 batched 16B loads, one LLC round-trip. Outputs early-clobber so they
// can't alias the address operands.
#define LD8(o0,o1,o2,o3,o4,o5,o6,o7,p0,p1,p2,p3,p4,p5,p6,p7)                     \
  asm volatile("global_load_dwordx4 %0, %8, off sc0 sc1\n\t"                     \
               "global_load_dwordx4 %1, %9, off sc0 sc1\n\t"                     \
               "global_load_dwordx4 %2, %10, off sc0 sc1\n\t"                    \
               "global_load_dwordx4 %3, %11, off sc0 sc1\n\t"                    \
               "global_load_dwordx4 %4, %12, off sc0 sc1\n\t"                    \
               "global_load_dwordx4 %5, %13, off sc0 sc1\n\t"                    \
               "global_load_dwordx4 %6, %14, off sc0 sc1\n\t"                    \
               "global_load_dwordx4 %7, %15, off sc0 sc1\n\t"                    \
               "s_waitcnt vmcnt(0)"                                              \
               : "=&v"(o0),"=&v"(o1),"=&v"(o2),"=&v"(o3),                        \
                 "=&v"(o4),"=&v"(o5),"=&v"(o6),"=&v"(o7)                         \
               : "v"(p0),"v"(p1),"v"(p2),"v"(p3),"v"(p4),"v"(p5),"v"(p6),"v"(p7) \
               : "memory")

#define LD2(o0,o1,p0,p1)                                                         \
  asm volatile("global_load_dwordx4 %0, %2, off sc0 sc1\n\t"                     \
               "global_load_dwordx4 %1, %3, off sc0 sc1\n\t"                     \
               "s_waitcnt vmcnt(0)"                                              \
               : "=&v"(o0),"=&v"(o1) : "v"(p0),"v"(p1) : "memory")

__device__ __forceinline__ void sc_store_short(unsigned short* p, unsigned short v) {
    asm volatile("global_store_short %0, %1, off sc0 sc1" :: "v"(p), "v"((unsigned)v) : "memory");
}
__device__ __forceinline__ void sc_store_dword(float* p, float v) {
    asm volatile("global_store_dword %0, %1, off sc0 sc1" :: "v"(p), "v"(v) : "memory");
}

// Monotonic-counter grid barrier. No cache maintenance: all cross-block data
// moves via sc0/sc1 (LLC-coherent) accesses, so only store-completion ordering
// (vmcnt) + one LLC atomic are needed. Counter never resets -> no reset race.
__device__ __forceinline__ void gbar(unsigned* cnt, unsigned tgt) {
    asm volatile("s_waitcnt vmcnt(0)" ::: "memory");   // every wave drains own sc-stores
    __syncthreads();
    if (threadIdx.x == 0) {
        __hip_atomic_fetch_add(cnt, 1u, __ATOMIC_RELAXED, __HIP_MEMORY_SCOPE_AGENT);
        while (__hip_atomic_load(cnt, __ATOMIC_RELAXED, __HIP_MEMORY_SCOPE_AGENT) < tgt) {}
    }
    __syncthreads();
}

__global__ void zero_kernel(float* __restrict__ p, int n) {
    int i = blockIdx.x * 256 + threadIdx.x;
    if (i < n) p[i] = 0.0f;
}

// W (= [Wx;Wh], 1280 x 4096) -> B-frag order [nb(256)][ku(40)][lane(64)][j(8)], hi/lo
__global__ void packW_kernel(const float* __restrict__ Wx, const float* __restrict__ Wh,
                             unsigned short* __restrict__ W0f, unsigned short* __restrict__ W1f) {
    int e = blockIdx.x * 256 + threadIdx.x;
    if (e >= 1280 * 4096) return;
    int k = e >> 12, n = e & 4095;
    float w = (k < NDIN) ? Wx[(size_t)k * NG + n] : Wh[(size_t)(k - NDIN) * NG + n];
    float back;
    unsigned short w0 = bf_hi(w, &back);
    unsigned short w1 = bf_hi(w - back, &back);
    int nb = n >> 4, nl = n & 15, ku = k >> 5, kr = k & 31;
    int lane = (kr >> 3) * 16 + nl, j = kr & 7;
    size_t off = (((size_t)nb * 40 + ku) * 64 + lane) * 8 + j;
    W0f[off] = w0; W1f[off] = w1;
}

// x ([64][512][256]) -> A-frag order [t][ku(8)][mb(4)][lane(64)][j(8)], hi/lo
__global__ void packX_kernel(const float* __restrict__ x,
                             unsigned short* __restrict__ xf0, unsigned short* __restrict__ xf1) {
    int e = blockIdx.x * 256 + threadIdx.x;
    if (e >= NB * NT * NDIN) return;
    int k = e & 255, t = (e >> 8) & 511, m = e >> 17;
    float v = x[e];
    float back;
    unsigned short a0 = bf_hi(v, &back);
    unsigned short a1 = bf_hi(v - back, &back);
    int ku = k >> 5, kr = k & 31, mb = m >> 4;
    int lane = (kr >> 3) * 16 + (m & 15), j = kr & 7;
    size_t off = ((((size_t)t * 8 + ku) * 4 + mb) * 64 + lane) * 8 + j;
    xf0[off] = a0; xf1[off] = a1;
}

// Wo (1024 x 256) -> B-frag order [nb(16)][ku(32)][lane(64)][j(8)], hi/lo
__global__ void packWo_kernel(const float* __restrict__ Wo,
                              unsigned short* __restrict__ Wo0f, unsigned short* __restrict__ Wo1f) {
    int e = blockIdx.x * 256 + threadIdx.x;
    if (e >= NH * NDOUT) return;
    int k = e >> 8, n = e & 255;
    float w = Wo[e];
    float back;
    unsigned short w0 = bf_hi(w, &back);
    unsigned short w1 = bf_hi(w - back, &back);
    int nb = n >> 4, nl = n & 15, ku = k >> 5, kr = k & 31;
    int lane = (kr >> 3) * 16 + nl, j = kr & 7;
    size_t off = (((size_t)nb * 32 + ku) * 64 + lane) * 8 + j;
    Wo0f[off] = w0; Wo1f[off] = w1;
}

// Persistent cooperative kernel, hand-rolled barrier. W/xf/Wo use normal cached
// loads (stay L2-resident across all 512 steps -- no buffer_inv ever executes);
// hf/opart (cross-block, cross-step) use sc0/sc1 LLC-coherent accesses only.
__global__ __launch_bounds__(512, 2) void persist_kernel(
    const unsigned short* __restrict__ W0f, const unsigned short* __restrict__ W1f,
    const unsigned short* __restrict__ xf0, const unsigned short* __restrict__ xf1,
    const unsigned short* __restrict__ Wo0f, const unsigned short* __restrict__ Wo1f,
    unsigned short* __restrict__ hf, float* __restrict__ cst,
    float* __restrict__ opart, const float* __restrict__ bias,
    const float* __restrict__ bo, float* __restrict__ out, unsigned* __restrict__ bar)
{
    extern __shared__ char dynlds[];
    float* red  = (float*)dynlds;                    // [8][4096]
    float* zfin = (float*)(dynlds + 131072);         // [4096]
    const unsigned short** tabA = (const unsigned short**)(dynlds + 147456); // [96]
    const unsigned short** tabW = tabA + 96;

    const int bid = blockIdx.x, tid = threadIdx.x;
    const int lane = tid & 63, w = tid >> 6;

    // proj blocks: t-invariant pointer tables, built once. buf-dependence is a
    // uniform +buf*65536-element offset applied in the loop.
    if (bid >= 64 && bid < 80) {
        const int pnb = bid - 64;
        for (int i = tid; i < 96; i += 512) {
            int q = i / 32, ku = i % 32, v = (q == 2);
            tabA[i] = hf + (((size_t)(v * 2) * 32 + ku) * 4) * 512;
            tabW[i] = ((q == 1) ? Wo1f : Wo0f) + (size_t)pnb * 32 * 512 + (size_t)ku * 512;
        }
        __syncthreads();
    }

    for (int t = 0; t <= NT + 1; ++t) {
        const int buf = t & 1, nbuf = (t + 1) & 1;

        if (bid < 64) {
            if (t < NT) {
                // ---- z + block-local combine: 16 h-cols (jt), all 4 gates, all rows ----
                const int jt = bid;
                float4v acc[4][4];                            // [mb][gate]
                #pragma unroll
                for (int mb = 0; mb < 4; ++mb)
                    #pragma unroll
                    for (int g = 0; g < 4; ++g)
                        acc[mb][g] = (float4v){0.f, 0.f, 0.f, 0.f};

                const int ku0 = w * 5;                        // wave-private K slice
                #pragma unroll
                for (int i = 0; i < 5; ++i) {
                    const int ku = ku0 + i;
                    short8 A0[4], A1[4], Wh[4], Wl[4];
                    if (ku < 8) {
                        // x contribution: read-only, L2-cached normal loads
                        const unsigned short* x0 = xf0 + ((size_t)t * 8 + ku) * 2048;
                        const unsigned short* x1 = xf1 + ((size_t)t * 8 + ku) * 2048;
                        #pragma unroll
                        for (int mb = 0; mb < 4; ++mb) {
                            A0[mb] = *(const short8*)(x0 + mb * 512 + lane * 8);
                            A1[mb] = *(const short8*)(x1 + mb * 512 + lane * 8);
                        }
                    } else {
                        // h contribution: cross-block per-step data -> LLC-coherent loads
                        const unsigned short* h0b = hf + ((size_t)buf * 32 + (ku - 8)) * 2048 + lane * 8;
                        const unsigned short* h1b = hf + ((size_t)(2 + buf) * 32 + (ku - 8)) * 2048 + lane * 8;
                        LD8(A0[0], A0[1], A0[2], A0[3], A1[0], A1[1], A1[2], A1[3],
                            h0b, h0b + 512, h0b + 1024, h0b + 1536,
                            h1b, h1b + 512, h1b + 1024, h1b + 1536);
                    }
                    #pragma unroll
                    for (int g = 0; g < 4; ++g) {
                        size_t off = (((size_t)(g * 64 + jt) * 40 + ku) * 64 + lane) * 8;
                        Wh[g] = *(const short8*)(W0f + off);
                        Wl[g] = *(const short8*)(W1f + off);
                    }
                    #pragma unroll
                    for (int mb = 0; mb < 4; ++mb)
                        #pragma unroll
                        for (int g = 0; g < 4; ++g) {
                            acc[mb][g] = __builtin_amdgcn_mfma_f32_16x16x32_bf16(A0[mb], Wh[g], acc[mb][g], 0, 0, 0);
                            acc[mb][g] = __builtin_amdgcn_mfma_f32_16x16x32_bf16(A0[mb], Wl[g], acc[mb][g], 0, 0, 0);
                            acc[mb][g] = __builtin_amdgcn_mfma_f32_16x16x32_bf16(A1[mb], Wh[g], acc[mb][g], 0, 0, 0);
                        }
                }

                // cross-wave splitK reduce via LDS
                {
                    float* slab = red + w * 4096;
                    #pragma unroll
                    for (int mb = 0; mb < 4; ++mb)
                        #pragma unroll
                        for (int g = 0; g < 4; ++g)
                            *(float4v*)&slab[((mb * 4 + g) * 64 + lane) * 4] = acc[mb][g];
                }
                __syncthreads();
                for (int s = tid; s < 1024; s += 512) {
                    float4v sum = (float4v){0.f, 0.f, 0.f, 0.f};
                    #pragma unroll
                    for (int ww = 0; ww < 8; ++ww)
                        sum = sum + *(const float4v*)&red[ww * 4096 + s * 4];
                    *(float4v*)&zfin[s * 4] = sum;
                }
                __syncthreads();

                // block-local gate math + cell update + h-frag write (LLC-coherent)
                for (int e = tid; e < 1024; e += 512) {
                    const int row = e >> 4, col = e & 15;
                    const int j = jt * 16 + col;
                    const int mb = row >> 4, q4 = (row >> 2) & 3, r = row & 3;
                    const int ln = q4 * 16 + col;
                    float zi = zfin[((mb * 4 + 0) * 64 + ln) * 4 + r] + bias[j];
                    float zf = zfin[((mb * 4 + 1) * 64 + ln) * 4 + r] + bias[NH + j];
                    float zg = zfin[((mb * 4 + 2) * 64 + ln) * 4 + r] + bias[2 * NH + j];
                    float zo = zfin[((mb * 4 + 3) * 64 + ln) * 4 + r] + bias[3 * NH + j];
                    float iv = sigf(zi), fv = sigf(zf), gv = tanhf(zg), ov = sigf(zo);
                    const size_t ci = (size_t)row * NH + j;   // block-exclusive columns: normal cached
                    float cv = fv * cst[ci] + iv * gv;
                    cst[ci] = cv;
                    float hv = ov * tanhf(cv);
                    float back;
                    unsigned short h0 = bf_hi(hv, &back);
                    unsigned short h1 = bf_hi(hv - back, &back);
                    const int ku = j >> 5, kr = j & 31;
                    const int lane2 = (kr >> 3) * 16 + (row & 15), jj = kr & 7;
                    size_t base = (((size_t)nbuf * 32 + ku) * 4 + mb) * 512 + lane2 * 8 + jj;
                    sc_store_short(hf + base, h0);
                    sc_store_short(hf + base + 131072, h1);   // v=1 plane
                }
            }
        } else if (bid < 80) {
            // ---- projection of hf[buf] (= h of step t-1) -> opart[t&1] ----
            if (t >= 1 && t <= NT) {
                const size_t bufofs = (size_t)buf * 65536;    // (buf*32)*4*512 elements
                const int pksl = w >> 2, mbw = w & 3;
                float4v pacc = (float4v){0.f, 0.f, 0.f, 0.f};
                #pragma unroll
                for (int bb = 0; bb < 6; ++bb) {
                    const int ibase = pksl * 48 + bb * 8;
                    short8 A[8];
                    const unsigned short* ap[8];
                    #pragma unroll
                    for (int u = 0; u < 8; ++u)
                        ap[u] = tabA[ibase + u] + bufofs + mbw * 512 + lane * 8;
                    LD8(A[0], A[1], A[2], A[3], A[4], A[5], A[6], A[7],
                        ap[0], ap[1], ap[2], ap[3], ap[4], ap[5], ap[6], ap[7]);
                    #pragma unroll
                    for (int u = 0; u < 8; ++u) {
                        short8 Bv = *(const short8*)(tabW[ibase + u] + lane * 8);
                        pacc = __builtin_amdgcn_mfma_f32_16x16x32_bf16(A[u], Bv, pacc, 0, 0, 0);
                    }
                }
                const int pnb = bid - 64;
                const int q4 = lane >> 4, nl16 = lane & 15;
                float* op = opart + (size_t)(t & 1) * 32768;
                #pragma unroll
                for (int r = 0; r < 4; ++r)
                    sc_store_dword(op + ((size_t)(pksl * 64 + mbw * 16 + q4 * 4 + r)) * NDOUT + pnb * 16 + nl16,
                                   pacc[r]);
            }
        } else {
            // ---- out-reduce of opart[(t-1)&1] (= proj of h step t-2) -> row t-2 ----
            if (t >= 2) {
                const int ob = bid - 80;
                const float* op = opart + (size_t)((t - 1) & 1) * 32768;
                int idx = ob * 512 + tid;                     // [0,4096)
                int m = idx >> 6, oc4 = (idx & 63) * 4;
                float4v s0, s1;
                LD2(s0, s1, &op[(size_t)m * NDOUT + oc4], &op[(size_t)(64 + m) * NDOUT + oc4]);
                float4v bv = *(const float4v*)&bo[oc4];
                float4v v = s0 + s1 + bv;
                float4v rr;
                rr[0] = fmaxf(v[0], 0.f); rr[1] = fmaxf(v[1], 0.f);
                rr[2] = fmaxf(v[2], 0.f); rr[3] = fmaxf(v[3], 0.f);
                *(float4v*)&out[((size_t)m * NT + (t - 2)) * NDOUT + oc4] = rr;
            }
        }

        gbar(bar, (unsigned)(t + 1) * GRIDN);
    }
}

extern "C" void kernel_launch(void* const* d_in, const int* in_sizes, int n_in,
                              void* d_out, int out_size, void* d_ws, size_t ws_size,
                              hipStream_t stream) {
    const float* x  = (const float*)d_in[0];
    const float* Wx = (const float*)d_in[1];
    const float* Wh = (const float*)d_in[2];
    const float* b  = (const float*)d_in[3];
    const float* Wo = (const float*)d_in[4];
    const float* bo = (const float*)d_in[5];
    float* out = (float*)d_out;
    char* ws = (char*)d_ws;

    size_t off = 0;
    float* cst    = (float*)(ws + off);               off += (size_t)NB * NH * 4;               // 256 KB
    unsigned short* hf = (unsigned short*)(ws + off); off += (size_t)2 * 2 * 32 * 4 * 512 * 2;  // 512 KB
    unsigned* bar = (unsigned*)(ws + off);            off += 256;                               // barrier line
    size_t zero_floats = off / 4;                     // cst + hf + bar zeroed
    float* opart = (float*)(ws + off);                off += (size_t)2 * 2 * NB * NDOUT * 4;    // 256 KB
    unsigned short* W0f = (unsigned short*)(ws + off); off += (size_t)1280 * 4096 * 2;
    unsigned short* W1f = (unsigned short*)(ws + off); off += (size_t)1280 * 4096 * 2;
    unsigned short* Wo0f = (unsigned short*)(ws + off); off += (size_t)NH * NDOUT * 2;
    unsigned short* Wo1f = (unsigned short*)(ws + off); off += (size_t)NH * NDOUT * 2;
    unsigned short* xf0 = (unsigned short*)(ws + off); off += (size_t)NB * NT * NDIN * 2;
    unsigned short* xf1 = (unsigned short*)(ws + off); off += (size_t)NB * NT * NDIN * 2;

    zero_kernel<<<(int)((zero_floats + 255) / 256), 256, 0, stream>>>((float*)ws, (int)zero_floats);
    packW_kernel<<<(1280 * 4096 + 255) / 256, 256, 0, stream>>>(Wx, Wh, W0f, W1f);
    packX_kernel<<<(NB * NT * NDIN + 255) / 256, 256, 0, stream>>>(x, xf0, xf1);
    packWo_kernel<<<(NH * NDOUT + 255) / 256, 256, 0, stream>>>(Wo, Wo0f, Wo1f);

    void* args[] = {(void*)&W0f, (void*)&W1f, (void*)&xf0, (void*)&xf1,
                    (void*)&Wo0f, (void*)&Wo1f, (void*)&hf, (void*)&cst,
                    (void*)&opart, (void*)&b, (void*)&bo, (void*)&out, (void*)&bar};
    hipLaunchCooperativeKernel((void*)persist_kernel, dim3(GRIDN), dim3(512),
                               args, (unsigned)LDSB, stream);
}

// Round 3
// 7157.179 us; speedup vs baseline: 1.4516x; 1.0193x over previous
//
#include <hip/hip_runtime.h>
#include <hip/hip_bf16.h>
#include <math.h>

#define NB 64
#define NT 512
#define NDIN 256
#define NH 1024
#define NG 4096
#define NDOUT 256

// grid roles: [0,64) z+combine, [64,80) proj, [80,88) out-reduce
#define GRIDN 88
#define LDSB_HIST 147456   // 128K reduce + 16K zfin
#define LDSB_FB   148992   // + 1.5K tables (fallback kernel)

#define HSTEP 131072       // shorts per h time-slab: [v(2)][ku(32)][mb(4)][512]

typedef __attribute__((ext_vector_type(8))) short short8;
typedef __attribute__((ext_vector_type(4))) float float4v;

__device__ __forceinline__ float sigf(float v) { return 1.0f / (1.0f + expf(-v)); }

__device__ __forceinline__ unsigned short bf_hi(float v, float* back) {
    __hip_bfloat16 b = __float2bfloat16(v);
    *back = __bfloat162float(b);
    union { __hip_bfloat16 b; unsigned short u; } cv; cv.b = b;
    return cv.u;
}

// ---- device-coherent (LLC) helpers ----
#define LD8(o0,o1,o2,o3,o4,o5,o6,o7,p0,p1,p2,p3,p4,p5,p6,p7)                     \
  asm volatile("global_load_dwordx4 %0, %8, off sc0 sc1\n\t"                     \
               "global_load_dwordx4 %1, %9, off sc0 sc1\n\t"                     \
               "global_load_dwordx4 %2, %10, off sc0 sc1\n\t"                    \
               "global_load_dwordx4 %3, %11, off sc0 sc1\n\t"                    \
               "global_load_dwordx4 %4, %12, off sc0 sc1\n\t"                    \
               "global_load_dwordx4 %5, %13, off sc0 sc1\n\t"                    \
               "global_load_dwordx4 %6, %14, off sc0 sc1\n\t"                    \
               "global_load_dwordx4 %7, %15, off sc0 sc1\n\t"                    \
               "s_waitcnt vmcnt(0)"                                              \
               : "=&v"(o0),"=&v"(o1),"=&v"(o2),"=&v"(o3),                        \
                 "=&v"(o4),"=&v"(o5),"=&v"(o6),"=&v"(o7)                         \
               : "v"(p0),"v"(p1),"v"(p2),"v"(p3),"v"(p4),"v"(p5),"v"(p6),"v"(p7) \
               : "memory")

#define LD2(o0,o1,p0,p1)                                                         \
  asm volatile("global_load_dwordx4 %0, %2, off sc0 sc1\n\t"                     \
               "global_load_dwordx4 %1, %3, off sc0 sc1\n\t"                     \
               "s_waitcnt vmcnt(0)"                                              \
               : "=&v"(o0),"=&v"(o1) : "v"(p0),"v"(p1) : "memory")

__device__ __forceinline__ void sc_store_short(unsigned short* p, unsigned short v) {
    asm volatile("global_store_short %0, %1, off sc0 sc1" :: "v"(p), "v"((unsigned)v) : "memory");
}
__device__ __forceinline__ void sc_store_dword(float* p, float v) {
    asm volatile("global_store_dword %0, %1, off sc0 sc1" :: "v"(p), "v"(v) : "memory");
}

// Monotonic-counter grid barrier. All cross-block data is either sc0/sc1
// (write-through, LLC) or written to fresh addresses each step (h history),
// so no cache maintenance is needed: drain own stores + one LLC atomic.
__device__ __forceinline__ void gbar(unsigned* cnt, unsigned tgt) {
    asm volatile("s_waitcnt vmcnt(0)" ::: "memory");
    __syncthreads();
    if (threadIdx.x == 0) {
        __hip_atomic_fetch_add(cnt, 1u, __ATOMIC_RELAXED, __HIP_MEMORY_SCOPE_AGENT);
        while (__hip_atomic_load(cnt, __ATOMIC_RELAXED, __HIP_MEMORY_SCOPE_AGENT) < tgt) {}
    }
    __syncthreads();
}

__global__ void zero_kernel(float* __restrict__ p, int n) {
    int i = blockIdx.x * 256 + threadIdx.x;
    if (i < n) p[i] = 0.0f;
}

// W (= [Wx;Wh], 1280 x 4096) -> B-frag order [nb(256)][ku(40)][lane(64)][j(8)], hi/lo
__global__ void packW_kernel(const float* __restrict__ Wx, const float* __restrict__ Wh,
                             unsigned short* __restrict__ W0f, unsigned short* __restrict__ W1f) {
    int e = blockIdx.x * 256 + threadIdx.x;
    if (e >= 1280 * 4096) return;
    int k = e >> 12, n = e & 4095;
    float w = (k < NDIN) ? Wx[(size_t)k * NG + n] : Wh[(size_t)(k - NDIN) * NG + n];
    float back;
    unsigned short w0 = bf_hi(w, &back);
    unsigned short w1 = bf_hi(w - back, &back);
    int nb = n >> 4, nl = n & 15, ku = k >> 5, kr = k & 31;
    int lane = (kr >> 3) * 16 + nl, j = kr & 7;
    size_t off = (((size_t)nb * 40 + ku) * 64 + lane) * 8 + j;
    W0f[off] = w0; W1f[off] = w1;
}

// x ([64][512][256]) -> A-frag order [t][ku(8)][mb(4)][lane(64)][j(8)], hi/lo
__global__ void packX_kernel(const float* __restrict__ x,
                             unsigned short* __restrict__ xf0, unsigned short* __restrict__ xf1) {
    int e = blockIdx.x * 256 + threadIdx.x;
    if (e >= NB * NT * NDIN) return;
    int k = e & 255, t = (e >> 8) & 511, m = e >> 17;
    float v = x[e];
    float back;
    unsigned short a0 = bf_hi(v, &back);
    unsigned short a1 = bf_hi(v - back, &back);
    int ku = k >> 5, kr = k & 31, mb = m >> 4;
    int lane = (kr >> 3) * 16 + (m & 15), j = kr & 7;
    size_t off = ((((size_t)t * 8 + ku) * 4 + mb) * 64 + lane) * 8 + j;
    xf0[off] = a0; xf1[off] = a1;
}

// Wo (1024 x 256) -> B-frag order [nb(16)][ku(32)][lane(64)][j(8)], hi/lo
__global__ void packWo_kernel(const float* __restrict__ Wo,
                              unsigned short* __restrict__ Wo0f, unsigned short* __restrict__ Wo1f) {
    int e = blockIdx.x * 256 + threadIdx.x;
    if (e >= NH * NDOUT) return;
    int k = e >> 8, n = e & 255;
    float w = Wo[e];
    float back;
    unsigned short w0 = bf_hi(w, &back);
    unsigned short w1 = bf_hi(w - back, &back);
    int nb = n >> 4, nl = n & 15, ku = k >> 5, kr = k & 31;
    int lane = (kr >> 3) * 16 + nl, j = kr & 7;
    size_t off = (((size_t)nb * 32 + ku) * 64 + lane) * 8 + j;
    Wo0f[off] = w0; Wo1f[off] = w1;
}

// ===================== history-buffer persistent kernel ======================
// h state gets a FRESH 256KB slab per timestep (hh + t*HSTEP). Readers use
// normal cached loads (address never seen before -> L2 miss -> fills from LLC
// with the value the writer pushed via sc0/sc1 write-through). The 8 z-blocks
// + 2 proj blocks pinned per XCD share one L2 fill of the h broadcast. W/xf/Wo
// stay permanently L2-resident (no invalidate ever runs).
__global__ __launch_bounds__(512, 2) void persist_hist_kernel(
    const unsigned short* __restrict__ W0f, const unsigned short* __restrict__ W1f,
    const unsigned short* __restrict__ xf0, const unsigned short* __restrict__ xf1,
    const unsigned short* __restrict__ Wo0f, const unsigned short* __restrict__ Wo1f,
    unsigned short* __restrict__ hh, float* __restrict__ cst,
    float* __restrict__ opart, const float* __restrict__ bias,
    const float* __restrict__ bo, float* __restrict__ out, unsigned* __restrict__ bar)
{
    extern __shared__ char dynlds[];
    float* red  = (float*)dynlds;                    // [8][4096]
    float* zfin = (float*)(dynlds + 131072);         // [4096]

    const int bid = blockIdx.x, tid = threadIdx.x;
    const int lane = tid & 63, w = tid >> 6;

    for (int t = 0; t <= NT + 1; ++t) {
        if (bid < 64) {
            if (t < NT) {
                // ---- z + block-local combine: 16 h-cols (jt), all 4 gates ----
                const int jt = bid;
                float4v acc[4][4];                            // [mb][gate]
                #pragma unroll
                for (int mb = 0; mb < 4; ++mb)
                    #pragma unroll
                    for (int g = 0; g < 4; ++g)
                        acc[mb][g] = (float4v){0.f, 0.f, 0.f, 0.f};

                const unsigned short* hbase = hh + (size_t)t * HSTEP;
                const int ku0 = w * 5;                        // wave-private K slice
                #pragma unroll
                for (int i = 0; i < 5; ++i) {
                    const int ku = ku0 + i;
                    short8 A0[4], A1[4], Wh[4], Wl[4];
                    const unsigned short *p0, *p1;
                    if (ku < 8) {
                        p0 = xf0 + ((size_t)t * 8 + ku) * 2048;
                        p1 = xf1 + ((size_t)t * 8 + ku) * 2048;
                    } else {
                        p0 = hbase + (size_t)(ku - 8) * 2048;
                        p1 = hbase + 65536 + (size_t)(ku - 8) * 2048;
                    }
                    #pragma unroll
                    for (int mb = 0; mb < 4; ++mb) {
                        A0[mb] = *(const short8*)(p0 + mb * 512 + lane * 8);
                        A1[mb] = *(const short8*)(p1 + mb * 512 + lane * 8);
                    }
                    #pragma unroll
                    for (int g = 0; g < 4; ++g) {
                        size_t off = (((size_t)(g * 64 + jt) * 40 + ku) * 64 + lane) * 8;
                        Wh[g] = *(const short8*)(W0f + off);
                        Wl[g] = *(const short8*)(W1f + off);
                    }
                    #pragma unroll
                    for (int mb = 0; mb < 4; ++mb)
                        #pragma unroll
                        for (int g = 0; g < 4; ++g) {
                            acc[mb][g] = __builtin_amdgcn_mfma_f32_16x16x32_bf16(A0[mb], Wh[g], acc[mb][g], 0, 0, 0);
                            acc[mb][g] = __builtin_amdgcn_mfma_f32_16x16x32_bf16(A0[mb], Wl[g], acc[mb][g], 0, 0, 0);
                            acc[mb][g] = __builtin_amdgcn_mfma_f32_16x16x32_bf16(A1[mb], Wh[g], acc[mb][g], 0, 0, 0);
                        }
                }

                // cross-wave splitK reduce via LDS
                {
                    float* slab = red + w * 4096;
                    #pragma unroll
                    for (int mb = 0; mb < 4; ++mb)
                        #pragma unroll
                        for (int g = 0; g < 4; ++g)
                            *(float4v*)&slab[((mb * 4 + g) * 64 + lane) * 4] = acc[mb][g];
                }
                __syncthreads();
                for (int s = tid; s < 1024; s += 512) {
                    float4v sum = (float4v){0.f, 0.f, 0.f, 0.f};
                    #pragma unroll
                    for (int ww = 0; ww < 8; ++ww)
                        sum = sum + *(const float4v*)&red[ww * 4096 + s * 4];
                    *(float4v*)&zfin[s * 4] = sum;
                }
                __syncthreads();

                // gate math + cell update + h write to FRESH slab t+1 (sc write-through)
                unsigned short* hw = hh + (size_t)(t + 1) * HSTEP;
                for (int e = tid; e < 1024; e += 512) {
                    const int row = e >> 4, col = e & 15;
                    const int j = jt * 16 + col;
                    const int mb = row >> 4, q4 = (row >> 2) & 3, r = row & 3;
                    const int ln = q4 * 16 + col;
                    float zi = zfin[((mb * 4 + 0) * 64 + ln) * 4 + r] + bias[j];
                    float zf = zfin[((mb * 4 + 1) * 64 + ln) * 4 + r] + bias[NH + j];
                    float zg = zfin[((mb * 4 + 2) * 64 + ln) * 4 + r] + bias[2 * NH + j];
                    float zo = zfin[((mb * 4 + 3) * 64 + ln) * 4 + r] + bias[3 * NH + j];
                    float iv = sigf(zi), fv = sigf(zf), gv = tanhf(zg), ov = sigf(zo);
                    const size_t ci = (size_t)row * NH + j;   // block-exclusive: normal cached
                    float cv = fv * cst[ci] + iv * gv;
                    cst[ci] = cv;
                    float hv = ov * tanhf(cv);
                    float back;
                    unsigned short h0 = bf_hi(hv, &back);
                    unsigned short h1 = bf_hi(hv - back, &back);
                    const int ku = j >> 5, kr = j & 31;
                    const int lane2 = (kr >> 3) * 16 + (row & 15), jj = kr & 7;
                    size_t base = ((size_t)ku * 4 + mb) * 512 + lane2 * 8 + jj;
                    sc_store_short(hw + base, h0);
                    sc_store_short(hw + base + 65536, h1);    // v=1 plane
                }
            }
        } else if (bid < 80) {
            // ---- projection of h slab t (= h of step t-1) -> opart[t&1] ----
            if (t >= 1 && t <= NT) {
                const int pnb = bid - 64;
                const unsigned short* hbase = hh + (size_t)t * HSTEP;
                const unsigned short* wb0 = Wo0f + (size_t)pnb * 32 * 512;
                const unsigned short* wb1 = Wo1f + (size_t)pnb * 32 * 512;
                const int pksl = w >> 2, mbw = w & 3;
                float4v pacc = (float4v){0.f, 0.f, 0.f, 0.f};
                #pragma unroll 8
                for (int i = pksl * 48; i < pksl * 48 + 48; ++i) {
                    const int q = i >> 5, ku = i & 31;
                    const unsigned short* ap = hbase + (q == 2 ? 65536 : 0)
                                             + (size_t)ku * 2048 + mbw * 512 + lane * 8;
                    const unsigned short* wp = ((q == 1) ? wb1 : wb0) + (size_t)ku * 512 + lane * 8;
                    pacc = __builtin_amdgcn_mfma_f32_16x16x32_bf16(
                        *(const short8*)ap, *(const short8*)wp, pacc, 0, 0, 0);
                }
                const int q4 = lane >> 4, nl16 = lane & 15;
                float* op = opart + (size_t)(t & 1) * 32768;
                #pragma unroll
                for (int r = 0; r < 4; ++r)
                    sc_store_dword(op + ((size_t)(pksl * 64 + mbw * 16 + q4 * 4 + r)) * NDOUT + pnb * 16 + nl16,
                                   pacc[r]);
            }
        } else {
            // ---- out-reduce of opart[(t-1)&1] -> row t-2 ----
            if (t >= 2) {
                const int ob = bid - 80;
                const float* op = opart + (size_t)((t - 1) & 1) * 32768;
                int idx = ob * 512 + tid;                     // [0,4096)
                int m = idx >> 6, oc4 = (idx & 63) * 4;
                float4v s0, s1;
                LD2(s0, s1, &op[(size_t)m * NDOUT + oc4], &op[(size_t)(64 + m) * NDOUT + oc4]);
                float4v bv = *(const float4v*)&bo[oc4];
                float4v v = s0 + s1 + bv;
                float4v rr;
                rr[0] = fmaxf(v[0], 0.f); rr[1] = fmaxf(v[1], 0.f);
                rr[2] = fmaxf(v[2], 0.f); rr[3] = fmaxf(v[3], 0.f);
                *(float4v*)&out[((size_t)m * NT + (t - 2)) * NDOUT + oc4] = rr;
            }
        }

        gbar(bar, (unsigned)(t + 1) * GRIDN);
    }
}

// ===================== fallback (round-2) kernel: used only if ws too small ==
__global__ __launch_bounds__(512, 2) void persist_kernel(
    const unsigned short* __restrict__ W0f, const unsigned short* __restrict__ W1f,
    const unsigned short* __restrict__ xf0, const unsigned short* __restrict__ xf1,
    const unsigned short* __restrict__ Wo0f, const unsigned short* __restrict__ Wo1f,
    unsigned short* __restrict__ hf, float* __restrict__ cst,
    float* __restrict__ opart, const float* __restrict__ bias,
    const float* __restrict__ bo, float* __restrict__ out, unsigned* __restrict__ bar)
{
    extern __shared__ char dynlds[];
    float* red  = (float*)dynlds;
    float* zfin = (float*)(dynlds + 131072);
    const unsigned short** tabA = (const unsigned short**)(dynlds + 147456);
    const unsigned short** tabW = tabA + 96;

    const int bid = blockIdx.x, tid = threadIdx.x;
    const int lane = tid & 63, w = tid >> 6;

    if (bid >= 64 && bid < 80) {
        const int pnb = bid - 64;
        for (int i = tid; i < 96; i += 512) {
            int q = i / 32, ku = i % 32, v = (q == 2);
            tabA[i] = hf + (((size_t)(v * 2) * 32 + ku) * 4) * 512;
            tabW[i] = ((q == 1) ? Wo1f : Wo0f) + (size_t)pnb * 32 * 512 + (size_t)ku * 512;
        }
        __syncthreads();
    }

    for (int t = 0; t <= NT + 1; ++t) {
        const int buf = t & 1, nbuf = (t + 1) & 1;
        if (bid < 64) {
            if (t < NT) {
                const int jt = bid;
                float4v acc[4][4];
                #pragma unroll
                for (int mb = 0; mb < 4; ++mb)
                    #pragma unroll
                    for (int g = 0; g < 4; ++g)
                        acc[mb][g] = (float4v){0.f, 0.f, 0.f, 0.f};
                const int ku0 = w * 5;
                #pragma unroll
                for (int i = 0; i < 5; ++i) {
                    const int ku = ku0 + i;
                    short8 A0[4], A1[4], Wh[4], Wl[4];
                    if (ku < 8) {
                        const unsigned short* x0 = xf0 + ((size_t)t * 8 + ku) * 2048;
                        const unsigned short* x1 = xf1 + ((size_t)t * 8 + ku) * 2048;
                        #pragma unroll
                        for (int mb = 0; mb < 4; ++mb) {
                            A0[mb] = *(const short8*)(x0 + mb * 512 + lane * 8);
                            A1[mb] = *(const short8*)(x1 + mb * 512 + lane * 8);
                        }
                    } else {
                        const unsigned short* h0b = hf + ((size_t)buf * 32 + (ku - 8)) * 2048 + lane * 8;
                        const unsigned short* h1b = hf + ((size_t)(2 + buf) * 32 + (ku - 8)) * 2048 + lane * 8;
                        LD8(A0[0], A0[1], A0[2], A0[3], A1[0], A1[1], A1[2], A1[3],
                            h0b, h0b + 512, h0b + 1024, h0b + 1536,
                            h1b, h1b + 512, h1b + 1024, h1b + 1536);
                    }
                    #pragma unroll
                    for (int g = 0; g < 4; ++g) {
                        size_t off = (((size_t)(g * 64 + jt) * 40 + ku) * 64 + lane) * 8;
                        Wh[g] = *(const short8*)(W0f + off);
                        Wl[g] = *(const short8*)(W1f + off);
                    }
                    #pragma unroll
                    for (int mb = 0; mb < 4; ++mb)
                        #pragma unroll
                        for (int g = 0; g < 4; ++g) {
                            acc[mb][g] = __builtin_amdgcn_mfma_f32_16x16x32_bf16(A0[mb], Wh[g], acc[mb][g], 0, 0, 0);
                            acc[mb][g] = __builtin_amdgcn_mfma_f32_16x16x32_bf16(A0[mb], Wl[g], acc[mb][g], 0, 0, 0);
                            acc[mb][g] = __builtin_amdgcn_mfma_f32_16x16x32_bf16(A1[mb], Wh[g], acc[mb][g], 0, 0, 0);
                        }
                }
                {
                    float* slab = red + w * 4096;
                    #pragma unroll
                    for (int mb = 0; mb < 4; ++mb)
                        #pragma unroll
                        for (int g = 0; g < 4; ++g)
                            *(float4v*)&slab[((mb * 4 + g) * 64 + lane) * 4] = acc[mb][g];
                }
                __syncthreads();
                for (int s = tid; s < 1024; s += 512) {
                    float4v sum = (float4v){0.f, 0.f, 0.f, 0.f};
                    #pragma unroll
                    for (int ww = 0; ww < 8; ++ww)
                        sum = sum + *(const float4v*)&red[ww * 4096 + s * 4];
                    *(float4v*)&zfin[s * 4] = sum;
                }
                __syncthreads();
                for (int e = tid; e < 1024; e += 512) {
                    const int row = e >> 4, col = e & 15;
                    const int j = jt * 16 + col;
                    const int mb = row >> 4, q4 = (row >> 2) & 3, r = row & 3;
                    const int ln = q4 * 16 + col;
                    float zi = zfin[((mb * 4 + 0) * 64 + ln) * 4 + r] + bias[j];
                    float zf = zfin[((mb * 4 + 1) * 64 + ln) * 4 + r] + bias[NH + j];
                    float zg = zfin[((mb * 4 + 2) * 64 + ln) * 4 + r] + bias[2 * NH + j];
                    float zo = zfin[((mb * 4 + 3) * 64 + ln) * 4 + r] + bias[3 * NH + j];
                    float iv = sigf(zi), fv = sigf(zf), gv = tanhf(zg), ov = sigf(zo);
                    const size_t ci = (size_t)row * NH + j;
                    float cv = fv * cst[ci] + iv * gv;
                    cst[ci] = cv;
                    float hv = ov * tanhf(cv);
                    float back;
                    unsigned short h0 = bf_hi(hv, &back);
                    unsigned short h1 = bf_hi(hv - back, &back);
                    const int ku = j >> 5, kr = j & 31;
                    const int lane2 = (kr >> 3) * 16 + (row & 15), jj = kr & 7;
                    size_t base = (((size_t)nbuf * 32 + ku) * 4 + mb) * 512 + lane2 * 8 + jj;
                    sc_store_short(hf + base, h0);
                    sc_store_short(hf + base + 131072, h1);
                }
            }
        } else if (bid < 80) {
            if (t >= 1 && t <= NT) {
                const size_t bufofs = (size_t)buf * 65536;
                const int pksl = w >> 2, mbw = w & 3;
                float4v pacc = (float4v){0.f, 0.f, 0.f, 0.f};
                #pragma unroll
                for (int bb = 0; bb < 6; ++bb) {
                    const int ibase = pksl * 48 + bb * 8;
                    short8 A[8];
                    const unsigned short* ap[8];
                    #pragma unroll
                    for (int u = 0; u < 8; ++u)
                        ap[u] = tabA[ibase + u] + bufofs + mbw * 512 + lane * 8;
                    LD8(A[0], A[1], A[2], A[3], A[4], A[5], A[6], A[7],
                        ap[0], ap[1], ap[2], ap[3], ap[4], ap[5], ap[6], ap[7]);
                    #pragma unroll
                    for (int u = 0; u < 8; ++u) {
                        short8 Bv = *(const short8*)(tabW[ibase + u] + lane * 8);
                        pacc = __builtin_amdgcn_mfma_f32_16x16x32_bf16(A[u], Bv, pacc, 0, 0, 0);
                    }
                }
                const int pnb = bid - 64;
                const int q4 = lane >> 4, nl16 = lane & 15;
                float* op = opart + (size_t)(t & 1) * 32768;
                #pragma unroll
                for (int r = 0; r < 4; ++r)
                    sc_store_dword(op + ((size_t)(pksl * 64 + mbw * 16 + q4 * 4 + r)) * NDOUT + pnb * 16 + nl16,
                                   pacc[r]);
            }
        } else {
            if (t >= 2) {
                const int ob = bid - 80;
                const float* op = opart + (size_t)((t - 1) & 1) * 32768;
                int idx = ob * 512 + tid;
                int m = idx >> 6, oc4 = (idx & 63) * 4;
                float4v s0, s1;
                LD2(s0, s1, &op[(size_t)m * NDOUT + oc4], &op[(size_t)(64 + m) * NDOUT + oc4]);
                float4v bv = *(const float4v*)&bo[oc4];
                float4v v = s0 + s1 + bv;
                float4v rr;
                rr[0] = fmaxf(v[0], 0.f); rr[1] = fmaxf(v[1], 0.f);
                rr[2] = fmaxf(v[2], 0.f); rr[3] = fmaxf(v[3], 0.f);
                *(float4v*)&out[((size_t)m * NT + (t - 2)) * NDOUT + oc4] = rr;
            }
        }
        gbar(bar, (unsigned)(t + 1) * GRIDN);
    }
}

extern "C" void kernel_launch(void* const* d_in, const int* in_sizes, int n_in,
                              void* d_out, int out_size, void* d_ws, size_t ws_size,
                              hipStream_t stream) {
    const float* x  = (const float*)d_in[0];
    const float* Wx = (const float*)d_in[1];
    const float* Wh = (const float*)d_in[2];
    const float* b  = (const float*)d_in[3];
    const float* Wo = (const float*)d_in[4];
    const float* bo = (const float*)d_in[5];
    float* out = (float*)d_out;
    char* ws = (char*)d_ws;

    // history layout sizing
    const size_t hh_bytes = (size_t)(NT + 1) * HSTEP * 2;     // 513 x 256 KB = 134.5 MB
    size_t need = 0;
    need += (size_t)NB * NH * 4;          // cst
    need += 256;                          // bar
    need += hh_bytes;                     // hh
    need += (size_t)2 * 2 * NB * NDOUT * 4;
    need += (size_t)1280 * 4096 * 2 * 2;  // W0f/W1f
    need += (size_t)NH * NDOUT * 2 * 2;   // Wo0f/Wo1f
    need += (size_t)NB * NT * NDIN * 2 * 2; // xf0/xf1

    if (ws_size >= need) {
        size_t off = 0;
        float* cst    = (float*)(ws + off);               off += (size_t)NB * NH * 4;   // 256 KB
        unsigned* bar = (unsigned*)(ws + off);            off += 256;
        unsigned short* hh = (unsigned short*)(ws + off); off += hh_bytes;
        size_t zero_floats = ((size_t)NB * NH * 4 + 256 + (size_t)HSTEP * 2) / 4; // cst+bar+hh[0]
        float* opart = (float*)(ws + off);                off += (size_t)2 * 2 * NB * NDOUT * 4;
        unsigned short* W0f = (unsigned short*)(ws + off); off += (size_t)1280 * 4096 * 2;
        unsigned short* W1f = (unsigned short*)(ws + off); off += (size_t)1280 * 4096 * 2;
        unsigned short* Wo0f = (unsigned short*)(ws + off); off += (size_t)NH * NDOUT * 2;
        unsigned short* Wo1f = (unsigned short*)(ws + off); off += (size_t)NH * NDOUT * 2;
        unsigned short* xf0 = (unsigned short*)(ws + off); off += (size_t)NB * NT * NDIN * 2;
        unsigned short* xf1 = (unsigned short*)(ws + off); off += (size_t)NB * NT * NDIN * 2;

        zero_kernel<<<(int)((zero_floats + 255) / 256), 256, 0, stream>>>((float*)ws, (int)zero_floats);
        packW_kernel<<<(1280 * 4096 + 255) / 256, 256, 0, stream>>>(Wx, Wh, W0f, W1f);
        packX_kernel<<<(NB * NT * NDIN + 255) / 256, 256, 0, stream>>>(x, xf0, xf1);
        packWo_kernel<<<(NH * NDOUT + 255) / 256, 256, 0, stream>>>(Wo, Wo0f, Wo1f);

        void* args[] = {(void*)&W0f, (void*)&W1f, (void*)&xf0, (void*)&xf1,
                        (void*)&Wo0f, (void*)&Wo1f, (void*)&hh, (void*)&cst,
                        (void*)&opart, (void*)&b, (void*)&bo, (void*)&out, (void*)&bar};
        hipLaunchCooperativeKernel((void*)persist_hist_kernel, dim3(GRIDN), dim3(512),
                                   args, (unsigned)LDSB_HIST, stream);
    } else {
        size_t off = 0;
        float* cst    = (float*)(ws + off);               off += (size_t)NB * NH * 4;
        unsigned short* hf = (unsigned short*)(ws + off); off += (size_t)2 * 2 * 32 * 4 * 512 * 2;
        unsigned* bar = (unsigned*)(ws + off);            off += 256;
        size_t zero_floats = off / 4;
        float* opart = (float*)(ws + off);                off += (size_t)2 * 2 * NB * NDOUT * 4;
        unsigned short* W0f = (unsigned short*)(ws + off); off += (size_t)1280 * 4096 * 2;
        unsigned short* W1f = (unsigned short*)(ws + off); off += (size_t)1280 * 4096 * 2;
        unsigned short* Wo0f = (unsigned short*)(ws + off); off += (size_t)NH * NDOUT * 2;
        unsigned short* Wo1f = (unsigned short*)(ws + off); off += (size_t)NH * NDOUT * 2;
        unsigned short* xf0 = (unsigned short*)(ws + off); off += (size_t)NB * NT * NDIN * 2;
        unsigned short* xf1 = (unsigned short*)(ws + off); off += (size_t)NB * NT * NDIN * 2;

        zero_kernel<<<(int)((zero_floats + 255) / 256), 256, 0, stream>>>((float*)ws, (int)zero_floats);
        packW_kernel<<<(1280 * 4096 + 255) / 256, 256, 0, stream>>>(Wx, Wh, W0f, W1f);
        packX_kernel<<<(NB * NT * NDIN + 255) / 256, 256, 0, stream>>>(x, xf0, xf1);
        packWo_kernel<<<(NH * NDOUT + 255) / 256, 256, 0, stream>>>(Wo, Wo0f, Wo1f);

        void* args[] = {(void*)&W0f, (void*)&W1f, (void*)&xf0, (void*)&xf1,
                        (void*)&Wo0f, (void*)&Wo1f, (void*)&hf, (void*)&cst,
                        (void*)&opart, (void*)&b, (void*)&bo, (void*)&out, (void*)&bar};
        hipLaunchCooperativeKernel((void*)persist_kernel, dim3(GRIDN), dim3(512),
                                   args, (unsigned)LDSB_FB, stream);
    }
}